// Round 3
// baseline (66.933 us; speedup 1.0000x reference)
//
#include <hip/hip_runtime.h>
#include <hip/hip_bf16.h>
#include <math.h>

// out[b] = bias + sum_{i,j} W[i,j] * leaky(cf[b,i]*pf[b,j]),  leaky(z)=0.55z+0.45|z|
// Contract over j first (no W transpose needed!):
//   Gp[b,i] = sum_j pf[b,j] W[i,j],  Hp[b,i] = sum_j |pf[b,j]| W[i,j]
//   out[b]  = bias + sum_i ( 0.55 cf[b,i] Gp[b,i] + 0.45 |cf[b,i]| Hp[b,i] )
// mfma(A=pf, B=W): A-frag lane holds row b, k=j contiguous (pf row-major OK);
// B-frag lane holds col n=i, k=j contiguous (W row-major OK). Single fused
// kernel: f32->bf16 convert in-register on load, |pf| = sign-bit clear on the
// A fragment (exact), f32 epilogue dot vs cf, atomicAdd partials (linear in
// Gp,Hp so j-split composes). Init kernel writes out=bias (atomics need a
// fresh zeroed/bias'd out every call).

constexpr int B = 256, D = 1024;
constexpr int BN = 32;          // i-tile width (N dim)
constexpr int JC = 64;          // j chunk (contraction split)
constexpr int NT = D / BN;      // 32
constexpr int KC = D / JC;      // 16  -> grid = 512 blocks, 2/CU

typedef __attribute__((ext_vector_type(8))) short bf16x8;
typedef __attribute__((ext_vector_type(4))) float f32x4;
typedef __attribute__((ext_vector_type(4))) int   int32x4;

__device__ __forceinline__ ushort f2bf(float x) {
    __hip_bfloat16 h = __float2bfloat16(x);
    return *reinterpret_cast<ushort*>(&h);
}

__device__ __forceinline__ bf16x8 cvt8(const float* __restrict__ p) {
    const float4 lo = *reinterpret_cast<const float4*>(p);
    const float4 hi = *reinterpret_cast<const float4*>(p + 4);
    bf16x8 v;
    v[0] = (short)f2bf(lo.x); v[1] = (short)f2bf(lo.y);
    v[2] = (short)f2bf(lo.z); v[3] = (short)f2bf(lo.w);
    v[4] = (short)f2bf(hi.x); v[5] = (short)f2bf(hi.y);
    v[6] = (short)f2bf(hi.z); v[7] = (short)f2bf(hi.w);
    return v;
}

__global__ __launch_bounds__(256) void opl_init(float* __restrict__ out,
                                                const float* __restrict__ bias) {
    out[threadIdx.x] = bias[0];
}

__global__ __launch_bounds__(256) void opl_main(
    const float* __restrict__ cf, const float* __restrict__ pf,
    const float* __restrict__ W, float* __restrict__ out)
{
    const int nt = blockIdx.x & (NT - 1);
    const int kc = blockIdx.x >> 5;          // / NT
    const int ibase = nt * BN, jbase = kc * JC;
    const int lane = threadIdx.x & 63;
    const int wid = threadIdx.x >> 6;
    const int mwave = wid * 64;              // 4 waves x 64 b-rows = 256 = B
    const int r16 = lane & 15;               // m (b) / n (i) index in fragment
    const int g = lane >> 4;                 // k-block for A/B; row-group for C/D

    f32x4 accG[4][2] = {};
    f32x4 accH[4][2] = {};

    #pragma unroll
    for (int ks = 0; ks < JC / 32; ++ks) {
        const int j0 = jbase + ks * 32 + g * 8;
        bf16x8 a[4], b[2];
        #pragma unroll
        for (int mf = 0; mf < 4; ++mf)
            a[mf] = cvt8(&pf[(size_t)(mwave + mf * 16 + r16) * D + j0]);
        #pragma unroll
        for (int nf = 0; nf < 2; ++nf)
            b[nf] = cvt8(&W[(size_t)(ibase + nf * 16 + r16) * D + j0]);
        #pragma unroll
        for (int mf = 0; mf < 4; ++mf) {
            int32x4 ai = __builtin_bit_cast(int32x4, a[mf]);
            ai &= 0x7fff7fff;                // |pf| exactly: clear bf16 sign bits
            const bf16x8 aa = __builtin_bit_cast(bf16x8, ai);
            #pragma unroll
            for (int nf = 0; nf < 2; ++nf) {
                accG[mf][nf] = __builtin_amdgcn_mfma_f32_16x16x32_bf16(a[mf], b[nf], accG[mf][nf], 0, 0, 0);
                accH[mf][nf] = __builtin_amdgcn_mfma_f32_16x16x32_bf16(aa,    b[nf], accH[mf][nf], 0, 0, 0);
            }
        }
    }

    // epilogue: C/D layout col=lane&15 -> i, row=(lane>>4)*4+r -> b.
    // s[mf][r] = sum over this lane's i-columns of 0.55 cf Gp + 0.45 |cf| Hp
    float s[4][4];
    #pragma unroll
    for (int mf = 0; mf < 4; ++mf)
        #pragma unroll
        for (int r = 0; r < 4; ++r) s[mf][r] = 0.f;

    #pragma unroll
    for (int mf = 0; mf < 4; ++mf) {
        #pragma unroll
        for (int nf = 0; nf < 2; ++nf) {
            #pragma unroll
            for (int r = 0; r < 4; ++r) {
                const int brow = mwave + mf * 16 + g * 4 + r;
                const float c = cf[(size_t)brow * D + ibase + nf * 16 + r16];
                s[mf][r] = fmaf(0.55f * c, accG[mf][nf][r],
                           fmaf(0.45f * fabsf(c), accH[mf][nf][r], s[mf][r]));
            }
        }
    }
    // reduce across the 16 column-lanes (xor masks < 16 stay in each g-group)
    #pragma unroll
    for (int mf = 0; mf < 4; ++mf) {
        #pragma unroll
        for (int r = 0; r < 4; ++r) {
            float v = s[mf][r];
            v += __shfl_xor(v, 1);
            v += __shfl_xor(v, 2);
            v += __shfl_xor(v, 4);
            v += __shfl_xor(v, 8);
            s[mf][r] = v;
        }
    }
    if (r16 == 0) {
        #pragma unroll
        for (int mf = 0; mf < 4; ++mf)
            #pragma unroll
            for (int r = 0; r < 4; ++r)
                atomicAdd(&out[mwave + mf * 16 + g * 4 + r], s[mf][r]);
    }
}

extern "C" void kernel_launch(void* const* d_in, const int* in_sizes, int n_in,
                              void* d_out, int out_size, void* d_ws, size_t ws_size,
                              hipStream_t stream) {
    const float* cf   = (const float*)d_in[0];
    const float* pf   = (const float*)d_in[1];
    const float* W    = (const float*)d_in[2];
    const float* bias = (const float*)d_in[3];
    float* out = (float*)d_out;

    opl_init<<<1, 256, 0, stream>>>(out, bias);
    opl_main<<<NT * KC, 256, 0, stream>>>(cf, pf, W, out);
}

// Round 4
// 63.206 us; speedup vs baseline: 1.0590x; 1.0590x over previous
//
#include <hip/hip_runtime.h>
#include <hip/hip_bf16.h>
#include <math.h>

// out[b] = bias + sum_{i,j} W[i,j] * leaky(cf[b,i]*pf[b,j]),  leaky(z)=0.55z+0.45|z|
// Contract over j (no W transpose):
//   Gp[b,i] = sum_j pf[b,j] W[i,j],  Hp[b,i] = sum_j |pf[b,j]| W[i,j]
//   out[b]  = bias + sum_i ( 0.55 cf[b,i] Gp[b,i] + 0.45 |cf[b,i]| Hp[b,i] )
// Round-4 fix vs round-3: fragments come from LDS (coalesced global->LDS
// staging with in-register f32->bf16 convert), not per-lane global gather at
// 4KB stride. LDS rows padded to 72 bf16 (144B stride: 16B-aligned for
// ds_read_b128, 36-bank stride -> <=2-way conflicts = free).

constexpr int B = 256, D = 1024;
constexpr int BN = 32;          // i-tile (MFMA N dim)
constexpr int JC = 64;          // j-chunk (contraction split)
constexpr int NT = D / BN;      // 32
constexpr int KC = D / JC;      // 16 -> grid 512, 2 blocks/CU
constexpr int LDP = 72;         // padded LDS row (bf16 elems)

typedef __attribute__((ext_vector_type(8))) short bf16x8;
typedef __attribute__((ext_vector_type(4))) float f32x4;
typedef __attribute__((ext_vector_type(4))) int   int32x4;

__device__ __forceinline__ ushort f2bf(float x) {
    __hip_bfloat16 h = __float2bfloat16(x);
    return *reinterpret_cast<ushort*>(&h);
}

__device__ __forceinline__ bf16x8 cvt8(float4 lo, float4 hi) {
    bf16x8 v;
    v[0] = (short)f2bf(lo.x); v[1] = (short)f2bf(lo.y);
    v[2] = (short)f2bf(lo.z); v[3] = (short)f2bf(lo.w);
    v[4] = (short)f2bf(hi.x); v[5] = (short)f2bf(hi.y);
    v[6] = (short)f2bf(hi.z); v[7] = (short)f2bf(hi.w);
    return v;
}

__global__ __launch_bounds__(256) void opl_init(float* __restrict__ out,
                                                const float* __restrict__ bias) {
    out[threadIdx.x] = bias[0];
}

__global__ __launch_bounds__(256) void opl_main(
    const float* __restrict__ cf, const float* __restrict__ pf,
    const float* __restrict__ W, float* __restrict__ out)
{
    __shared__ ushort sP[B][LDP];   // pf tile  [256][72] bf16 = 36.0 KB
    __shared__ ushort sW[BN][LDP];  // W  tile  [ 32][72] bf16 =  4.5 KB

    const int nt = blockIdx.x & (NT - 1);
    const int kc = blockIdx.x >> 5;
    const int ibase = nt * BN, jbase = kc * JC;
    const int t = threadIdx.x;

    // ---- stage: coalesced f32 loads (8 threads/row = 256B runs), cvt, LDS ----
    {
        const int r = t >> 3, c = (t & 7) * 8;
        const float* src = &W[(size_t)(ibase + r) * D + jbase + c];
        const float4 lo = *reinterpret_cast<const float4*>(src);
        const float4 hi = *reinterpret_cast<const float4*>(src + 4);
        *reinterpret_cast<bf16x8*>(&sW[r][c]) = cvt8(lo, hi);
    }
    #pragma unroll
    for (int p = 0; p < 8; ++p) {
        const int r = p * 32 + (t >> 3), c = (t & 7) * 8;
        const float* src = &pf[(size_t)r * D + jbase + c];
        const float4 lo = *reinterpret_cast<const float4*>(src);
        const float4 hi = *reinterpret_cast<const float4*>(src + 4);
        *reinterpret_cast<bf16x8*>(&sP[r][c]) = cvt8(lo, hi);
    }
    __syncthreads();

    // ---- MFMA: wave = 64 b-rows x 32 i-cols, K = JC ----
    const int lane = t & 63;
    const int wid = t >> 6;
    const int mwave = wid * 64;     // 4 waves cover all 256 b
    const int r16 = lane & 15;      // m/n index within fragment
    const int g = lane >> 4;        // k-block for A/B; row-group for C/D

    f32x4 accG[4][2] = {};
    f32x4 accH[4][2] = {};

    #pragma unroll
    for (int ks = 0; ks < JC / 32; ++ks) {
        const int c0 = ks * 32 + g * 8;
        bf16x8 a[4], b[2];
        #pragma unroll
        for (int mf = 0; mf < 4; ++mf)
            a[mf] = *reinterpret_cast<const bf16x8*>(&sP[mwave + mf * 16 + r16][c0]);
        #pragma unroll
        for (int nf = 0; nf < 2; ++nf)
            b[nf] = *reinterpret_cast<const bf16x8*>(&sW[nf * 16 + r16][c0]);
        #pragma unroll
        for (int mf = 0; mf < 4; ++mf) {
            int32x4 ai = __builtin_bit_cast(int32x4, a[mf]);
            ai &= 0x7fff7fff;       // |pf| exactly: clear bf16 sign bits
            const bf16x8 aa = __builtin_bit_cast(bf16x8, ai);
            #pragma unroll
            for (int nf = 0; nf < 2; ++nf) {
                accG[mf][nf] = __builtin_amdgcn_mfma_f32_16x16x32_bf16(a[mf], b[nf], accG[mf][nf], 0, 0, 0);
                accH[mf][nf] = __builtin_amdgcn_mfma_f32_16x16x32_bf16(aa,    b[nf], accH[mf][nf], 0, 0, 0);
            }
        }
    }

    // ---- epilogue: C/D col=lane&15 -> i, row=(lane>>4)*4+r -> b ----
    float s[4][4];
    #pragma unroll
    for (int mf = 0; mf < 4; ++mf)
        #pragma unroll
        for (int r = 0; r < 4; ++r) s[mf][r] = 0.f;

    #pragma unroll
    for (int mf = 0; mf < 4; ++mf) {
        #pragma unroll
        for (int nf = 0; nf < 2; ++nf) {
            #pragma unroll
            for (int r = 0; r < 4; ++r) {
                const int brow = mwave + mf * 16 + g * 4 + r;
                const float c = cf[(size_t)brow * D + ibase + nf * 16 + r16];
                s[mf][r] = fmaf(0.55f * c, accG[mf][nf][r],
                           fmaf(0.45f * fabsf(c), accH[mf][nf][r], s[mf][r]));
            }
        }
    }
    #pragma unroll
    for (int mf = 0; mf < 4; ++mf) {
        #pragma unroll
        for (int r = 0; r < 4; ++r) {
            float v = s[mf][r];
            v += __shfl_xor(v, 1);
            v += __shfl_xor(v, 2);
            v += __shfl_xor(v, 4);
            v += __shfl_xor(v, 8);
            s[mf][r] = v;
        }
    }
    if (r16 == 0) {
        #pragma unroll
        for (int mf = 0; mf < 4; ++mf)
            #pragma unroll
            for (int r = 0; r < 4; ++r)
                atomicAdd(&out[mwave + mf * 16 + g * 4 + r], s[mf][r]);
    }
}

extern "C" void kernel_launch(void* const* d_in, const int* in_sizes, int n_in,
                              void* d_out, int out_size, void* d_ws, size_t ws_size,
                              hipStream_t stream) {
    const float* cf   = (const float*)d_in[0];
    const float* pf   = (const float*)d_in[1];
    const float* W    = (const float*)d_in[2];
    const float* bias = (const float*)d_in[3];
    float* out = (float*)d_out;

    opl_init<<<1, 256, 0, stream>>>(out, bias);
    opl_main<<<NT * KC, 256, 0, stream>>>(cf, pf, W, out);
}

// Round 5
// 12.655 us; speedup vs baseline: 5.2892x; 4.9946x over previous
//
#include <hip/hip_runtime.h>
#include <hip/hip_bf16.h>
#include <math.h>

// out[b] = bias + sum_{i,j} W[i,j] * leaky(cf[b,i]*pf[b,j]),  leaky(z)=0.55z+0.45|z|
// Contract over j (no W transpose):
//   Gp[b,i] = sum_j pf[b,j] W[i,j],  Hp[b,i] = sum_j |pf[b,j]| W[i,j]
//   out[b]  = bias + sum_i ( 0.55 cf[b,i] Gp[b,i] + 0.45 |cf[b,i]| Hp[b,i] )
// Round-5 fix vs round-4: the 131072 atomicAdds onto 16 cachelines (512
// serialized RMWs per word -> WRITE_SIZE 2 MB for 1 KB of output) were the
// entire kernel time. Replaced with plain stores of per-block partials to
// ws[b][block] (512 KB, fully rewritten every call) + a wave-per-row reduce
// kernel that also applies bias (init dispatch gone).

constexpr int B = 256, D = 1024;
constexpr int BN = 32;          // i-tile (MFMA N dim)
constexpr int JC = 64;          // j-chunk (contraction split)
constexpr int NT = D / BN;      // 32
constexpr int KC = D / JC;      // 16
constexpr int NBLK = NT * KC;   // 512 partial sets
constexpr int LDP = 72;         // padded LDS row (bf16 elems)

typedef __attribute__((ext_vector_type(8))) short bf16x8;
typedef __attribute__((ext_vector_type(4))) float f32x4;
typedef __attribute__((ext_vector_type(4))) int   int32x4;

__device__ __forceinline__ ushort f2bf(float x) {
    __hip_bfloat16 h = __float2bfloat16(x);
    return *reinterpret_cast<ushort*>(&h);
}

__device__ __forceinline__ bf16x8 cvt8(float4 lo, float4 hi) {
    bf16x8 v;
    v[0] = (short)f2bf(lo.x); v[1] = (short)f2bf(lo.y);
    v[2] = (short)f2bf(lo.z); v[3] = (short)f2bf(lo.w);
    v[4] = (short)f2bf(hi.x); v[5] = (short)f2bf(hi.y);
    v[6] = (short)f2bf(hi.z); v[7] = (short)f2bf(hi.w);
    return v;
}

__global__ __launch_bounds__(256) void opl_main(
    const float* __restrict__ cf, const float* __restrict__ pf,
    const float* __restrict__ W, float* __restrict__ ws)
{
    __shared__ ushort sP[B][LDP];   // pf tile  [256][72] bf16 = 36.0 KB
    __shared__ ushort sW[BN][LDP];  // W  tile  [ 32][72] bf16 =  4.5 KB

    const int nt = blockIdx.x & (NT - 1);
    const int kc = blockIdx.x >> 5;
    const int ibase = nt * BN, jbase = kc * JC;
    const int t = threadIdx.x;

    // ---- stage: coalesced f32 loads (8 threads/row = 256B runs), cvt, LDS ----
    {
        const int r = t >> 3, c = (t & 7) * 8;
        const float* src = &W[(size_t)(ibase + r) * D + jbase + c];
        const float4 lo = *reinterpret_cast<const float4*>(src);
        const float4 hi = *reinterpret_cast<const float4*>(src + 4);
        *reinterpret_cast<bf16x8*>(&sW[r][c]) = cvt8(lo, hi);
    }
    #pragma unroll
    for (int p = 0; p < 8; ++p) {
        const int r = p * 32 + (t >> 3), c = (t & 7) * 8;
        const float* src = &pf[(size_t)r * D + jbase + c];
        const float4 lo = *reinterpret_cast<const float4*>(src);
        const float4 hi = *reinterpret_cast<const float4*>(src + 4);
        *reinterpret_cast<bf16x8*>(&sP[r][c]) = cvt8(lo, hi);
    }
    __syncthreads();

    // ---- MFMA: wave = 64 b-rows x 32 i-cols, K = JC ----
    const int lane = t & 63;
    const int wid = t >> 6;
    const int mwave = wid * 64;     // 4 waves cover all 256 b
    const int r16 = lane & 15;      // m/n index within fragment
    const int g = lane >> 4;        // k-block for A/B; row-group for C/D

    f32x4 accG[4][2] = {};
    f32x4 accH[4][2] = {};

    #pragma unroll
    for (int ks = 0; ks < JC / 32; ++ks) {
        const int c0 = ks * 32 + g * 8;
        bf16x8 a[4], b[2];
        #pragma unroll
        for (int mf = 0; mf < 4; ++mf)
            a[mf] = *reinterpret_cast<const bf16x8*>(&sP[mwave + mf * 16 + r16][c0]);
        #pragma unroll
        for (int nf = 0; nf < 2; ++nf)
            b[nf] = *reinterpret_cast<const bf16x8*>(&sW[nf * 16 + r16][c0]);
        #pragma unroll
        for (int mf = 0; mf < 4; ++mf) {
            int32x4 ai = __builtin_bit_cast(int32x4, a[mf]);
            ai &= 0x7fff7fff;       // |pf| exactly: clear bf16 sign bits
            const bf16x8 aa = __builtin_bit_cast(bf16x8, ai);
            #pragma unroll
            for (int nf = 0; nf < 2; ++nf) {
                accG[mf][nf] = __builtin_amdgcn_mfma_f32_16x16x32_bf16(a[mf], b[nf], accG[mf][nf], 0, 0, 0);
                accH[mf][nf] = __builtin_amdgcn_mfma_f32_16x16x32_bf16(aa,    b[nf], accH[mf][nf], 0, 0, 0);
            }
        }
    }

    // ---- epilogue: C/D col=lane&15 -> i, row=(lane>>4)*4+r -> b ----
    float s[4][4];
    #pragma unroll
    for (int mf = 0; mf < 4; ++mf)
        #pragma unroll
        for (int r = 0; r < 4; ++r) s[mf][r] = 0.f;

    #pragma unroll
    for (int mf = 0; mf < 4; ++mf) {
        #pragma unroll
        for (int nf = 0; nf < 2; ++nf) {
            #pragma unroll
            for (int r = 0; r < 4; ++r) {
                const int brow = mwave + mf * 16 + g * 4 + r;
                const float c = cf[(size_t)brow * D + ibase + nf * 16 + r16];
                s[mf][r] = fmaf(0.55f * c, accG[mf][nf][r],
                           fmaf(0.45f * fabsf(c), accH[mf][nf][r], s[mf][r]));
            }
        }
    }
    #pragma unroll
    for (int mf = 0; mf < 4; ++mf) {
        #pragma unroll
        for (int r = 0; r < 4; ++r) {
            float v = s[mf][r];
            v += __shfl_xor(v, 1);
            v += __shfl_xor(v, 2);
            v += __shfl_xor(v, 4);
            v += __shfl_xor(v, 8);
            s[mf][r] = v;
        }
    }
    // plain stores of per-block partials: ws[b][block]; no atomics
    if (r16 == 0) {
        #pragma unroll
        for (int mf = 0; mf < 4; ++mf)
            #pragma unroll
            for (int r = 0; r < 4; ++r)
                ws[(size_t)(mwave + mf * 16 + g * 4 + r) * NBLK + blockIdx.x] = s[mf][r];
    }
}

// one wave per batch row: sum 512 contiguous partials + bias
__global__ __launch_bounds__(256) void opl_reduce(
    const float* __restrict__ ws, const float* __restrict__ bias,
    float* __restrict__ out)
{
    const int wid = threadIdx.x >> 6, lane = threadIdx.x & 63;
    const int b = blockIdx.x * 4 + wid;
    const float* p = ws + (size_t)b * NBLK;
    float s = 0.f;
    #pragma unroll
    for (int k = 0; k < NBLK / 64; ++k) s += p[lane + k * 64];
    #pragma unroll
    for (int off = 1; off < 64; off <<= 1) s += __shfl_xor(s, off);
    if (lane == 0) out[b] = s + bias[0];
}

extern "C" void kernel_launch(void* const* d_in, const int* in_sizes, int n_in,
                              void* d_out, int out_size, void* d_ws, size_t ws_size,
                              hipStream_t stream) {
    const float* cf   = (const float*)d_in[0];
    const float* pf   = (const float*)d_in[1];
    const float* W    = (const float*)d_in[2];
    const float* bias = (const float*)d_in[3];
    float* out = (float*)d_out;
    float* ws  = (float*)d_ws;   // B * NBLK * 4 = 512 KB, fully rewritten each call

    opl_main<<<NT * KC, 256, 0, stream>>>(cf, pf, W, ws);
    opl_reduce<<<B / 4, 256, 0, stream>>>(ws, bias, out);
}